// Round 3
// baseline (284.521 us; speedup 1.0000x reference)
//
#include <hip/hip_runtime.h>
#include <cstdint>

#define BATCHES 8
#define NPTS 2048
#define NF 512
#define KNN 32
#define BWAVES 4   // 256-thread block = 4 waves
#define QPW 2      // queries per wave: deep pipeline (gather A || FULL select B)

// grid = 8 batches * 256 chunks = 2048 blocks; batch = blockIdx & 7 (XCD L2 affinity).
// 8 blocks/CU queued, 4 resident (LDS 35328 B) -> backfill smooths drain tail.
// Fused loop: each of 8 chunks = {issue 8 gather loads (vmcnt)} -> {select-B piece
// (VALU + lgkmcnt shuffles, independent)} -> {fmax consume}. Select-B is fully
// hidden under gather-A's L2 traffic; gather is the ~27 TB/s L2 floor.
// launch_bounds(256,4) = 128 VGPR hard cap; spill shows up as WRITE_SIZE > 32 MB.
// (R2 resubmission: prior bench was an infra failure, no counters returned.)

typedef float vfloat4 __attribute__((ext_vector_type(4)));  // native vec for nt-store

__global__ __launch_bounds__(256, 4)
void pointnetpp_knn_maxpool(const float* __restrict__ x,
                            const float* __restrict__ points,
                            float* __restrict__ out) {
    __shared__ __align__(16) float    pts4[NPTS * 4];      // [N][4]: one b128/candidate
    __shared__ __align__(16) uint64_t ckey[BWAVES][64];    // candidate keys (fast path)
    __shared__ __align__(16) int      sel[BWAVES][KNN];    // tie-fallback emit only

    const int tid  = threadIdx.x;
    const int lane = tid & 63;
    const int w    = tid >> 6;

    const int b     = blockIdx.x & 7;
    const int chunk = blockIdx.x >> 3;

    // ---- stage points[b] into LDS as [N][4] (pad .w) ----
    {
        const float* src = points + (size_t)b * NPTS * 3;
        for (int p = tid; p < NPTS; p += 256) {
            float4* d = (float4*)&pts4[p * 4];
            *d = make_float4(src[p * 3 + 0], src[p * 3 + 1], src[p * 3 + 2], 0.f);
        }
    }
    __syncthreads();

    const uint64_t lmlt = (1ull << lane) - 1ull;
    const float*   xb   = x + (size_t)b * NPTS * NF;

    const int iA = (chunk * BWAVES + w) * QPW;   // this wave's queries: iA, iA+1

    uint32_t db[32];   // shared across A and B (register-resident)

    auto countLE = [&](uint32_t t) -> uint32_t {
        uint32_t c = 0;
        #pragma unroll
        for (int j = 0; j < 32; ++j)
            c += (uint32_t)__builtin_popcountll(__ballot(db[j] <= t));
        return c;
    };

    auto distTo = [&](int qi) {
        const float4 qp = *(const float4*)&pts4[qi * 4];
        #pragma unroll
        for (int j = 0; j < 32; ++j) {
            const int n = lane + (j << 6);
            const float4 pp = *(const float4*)&pts4[n * 4];
            const float dx = qp.x - pp.x;
            const float dy = qp.y - pp.y;
            const float dz = qp.z - pp.z;
            db[j] = __float_as_uint(dx * dx + dy * dy + dz * dz);
        }
    };

    // compact <=64 candidates (d2<=thr) to LDS keys, then TOP-32 MERGE-SELECT:
    // bitonic stages k=2..32 sort halves in opposite directions (15 rounds),
    // one j=32 min-merge picks the 32 smallest (UNORDERED - maxpool is
    // order-invariant). Saves the 5 rounds of the full k=64 sort. Requires
    // 32 <= cthr <= 64 so lanes 0..31 hold real keys.
    auto compactSelect = [&](uint32_t thr, uint32_t cthr) -> int {
        uint32_t base = 0;
        #pragma unroll
        for (int j = 0; j < 32; ++j) {
            const bool     p = db[j] <= thr;
            const uint64_t m = __ballot(p);
            if (p) {
                const int slot = (int)base + (int)__popcll(m & lmlt);
                ckey[w][slot] = (((uint64_t)db[j]) << 11) | (uint64_t)(lane + (j << 6));
            }
            base += (uint32_t)__builtin_popcountll(m);
        }
        uint64_t key = (lane < (int)cthr) ? ckey[w][lane] : ~0ull;
        #pragma unroll
        for (int k = 2; k <= 32; k <<= 1) {
            #pragma unroll
            for (int j = k >> 1; j > 0; j >>= 1) {
                const uint64_t other = __shfl_xor((unsigned long long)key, j);
                const bool takeMin = (((lane & j) == 0) == ((lane & k) == 0));
                key = ((key < other) == takeMin) ? key : other;
            }
        }
        {   // min-merge: lanes 0..31 take the 32 smallest
            const uint64_t other = __shfl_xor((unsigned long long)key, 32);
            const uint64_t mn = key < other ? key : other;
            const uint64_t mx = key < other ? other : key;
            key = ((lane & 32) == 0) ? mn : mx;
        }
        return (int)(key & 0x7FFull);
    };

    // exact-tie fallback: all <T, then ==T ascending index (ref tie order)
    auto tieFallback = [&](uint32_t T, int cnt_lt) -> int {
        int base_lt = 0, base_eq = 0;
        #pragma unroll
        for (int j = 0; j < 32; ++j) {
            const bool lt = db[j] < T;
            const bool eq = db[j] == T;
            const uint64_t mlt = __ballot(lt);
            const uint64_t meq = __ballot(eq);
            int slot = -1;
            if (lt)      slot = base_lt + (int)__popcll(mlt & lmlt);
            else if (eq) slot = cnt_lt + base_eq + (int)__popcll(meq & lmlt);
            if (slot >= 0 && slot < KNN) sel[w][slot] = lane + (j << 6);
            base_lt += (int)__popcll(mlt);
            base_eq += (int)__popcll(meq);
        }
        return sel[w][lane & (KNN - 1)];
    };

    // full select on current db[] (probe fast path + binary-search + tie fallback)
    auto selectFull = [&]() -> int {
        uint32_t lmin = db[0];
        #pragma unroll
        for (int j = 1; j < 32; ++j) lmin = min(lmin, db[j]);
        uint32_t sm = lmin;
        #pragma unroll
        for (int k = 2; k <= 64; k <<= 1) {
            #pragma unroll
            for (int j = k >> 1; j > 0; j >>= 1) {
                const uint32_t o  = (uint32_t)__shfl_xor((int)sm, j);
                const uint32_t mn = min(sm, o);
                const uint32_t mx = max(sm, o);
                sm = (((lane & j) == 0) == ((lane & k) == 0)) ? mn : mx;
            }
        }
        const uint32_t probe = (uint32_t)__builtin_amdgcn_readlane((int)sm, 31);
        const uint32_t hi0   = (uint32_t)__builtin_amdgcn_readlane((int)sm, 63);

        const uint32_t c1 = countLE(probe);          // >= 32 guaranteed
        if (c1 <= 64u) return compactSelect(probe, c1);
        const uint32_t cs = countLE(hi0);            // >= 64 guaranteed
        if (cs <= 64u) return compactSelect(hi0, cs);
        if (probe == 0u) return tieFallback(0u, 0);  // >=65 zero-distance dups
        uint32_t lo = 0u, hi = probe;                // c(lo)<32 (self only), c(hi)>64
        while (hi - lo > 1u) {
            const uint32_t mid = lo + ((hi - lo) >> 1);
            const uint32_t c   = countLE(mid);
            if (c >= KNN && c <= 64u) return compactSelect(mid, c);
            if (c > 64u) hi = mid; else lo = mid;
        }
        return tieFallback(hi, (int)countLE(lo));    // count(<=lo) == count(<hi)
    };

    // ================= query A: distances + select (unhidden) =================
    distTo(iA);
    const int selvA = selectFull();

    // ===== fused: gather+maxpool A (VMEM) || FULL select B (VALU/LDS) =====
    const float4 qpB = *(const float4*)&pts4[(iA + 1) * 4];
    float4 a0 = make_float4(-INFINITY, -INFINITY, -INFINITY, -INFINITY);
    float4 a1 = a0;

    // select-B state carried across chunks (SSA after full unroll)
    uint32_t smB = 0, probeB = 0, hi0B = 0, c1B = 0, baseB = 0;
    bool     haveB = false;
    uint64_t keyB = ~0ull;

    #pragma unroll   // FULL unroll: db[] and chunk-id must be compile-time
    for (int cc = 0; cc < 8; ++cc) {
        // --- issue 8 gather loads for rows 4cc..4cc+3 (vmcnt, independent) ---
        const int r0 = cc * 4;
        const int n0 = __builtin_amdgcn_readlane(selvA, r0 + 0) & (NPTS - 1);
        const int n1 = __builtin_amdgcn_readlane(selvA, r0 + 1) & (NPTS - 1);
        const int n2 = __builtin_amdgcn_readlane(selvA, r0 + 2) & (NPTS - 1);
        const int n3 = __builtin_amdgcn_readlane(selvA, r0 + 3) & (NPTS - 1);
        const float4* p0 = (const float4*)(xb + (size_t)n0 * NF);
        const float4* p1 = (const float4*)(xb + (size_t)n1 * NF);
        const float4* p2 = (const float4*)(xb + (size_t)n2 * NF);
        const float4* p3 = (const float4*)(xb + (size_t)n3 * NF);
        const float4 u00 = p0[lane], u01 = p0[lane + 64];
        const float4 u10 = p1[lane], u11 = p1[lane + 64];
        const float4 u20 = p2[lane], u21 = p2[lane + 64];
        const float4 u30 = p3[lane], u31 = p3[lane + 64];

        // --- select-B piece cc (no dependence on the loads above) ---
        if (cc == 0 || cc == 1) {         // distances, 16 per chunk
            #pragma unroll
            for (int jj = 0; jj < 16; ++jj) {
                const int j = cc * 16 + jj;
                const int n = lane + (j << 6);
                const float4 pp = *(const float4*)&pts4[n * 4];
                const float dx = qpB.x - pp.x;
                const float dy = qpB.y - pp.y;
                const float dz = qpB.z - pp.z;
                db[j] = __float_as_uint(dx * dx + dy * dy + dz * dz);
            }
        } else if (cc == 2) {             // lane-min + full sort64 of minima
            uint32_t lmin = db[0];
            #pragma unroll
            for (int j = 1; j < 32; ++j) lmin = min(lmin, db[j]);
            uint32_t sm = lmin;
            #pragma unroll
            for (int k = 2; k <= 64; k <<= 1) {
                #pragma unroll
                for (int j = k >> 1; j > 0; j >>= 1) {
                    const uint32_t o  = (uint32_t)__shfl_xor((int)sm, j);
                    const uint32_t mn = min(sm, o);
                    const uint32_t mx = max(sm, o);
                    sm = (((lane & j) == 0) == ((lane & k) == 0)) ? mn : mx;
                }
            }
            smB = sm;
        } else if (cc == 3) {             // probe + window count
            probeB = (uint32_t)__builtin_amdgcn_readlane((int)smB, 31);
            hi0B   = (uint32_t)__builtin_amdgcn_readlane((int)smB, 63);
            c1B    = countLE(probeB);     // >= 32 guaranteed
            haveB  = (c1B <= 64u);
            baseB  = 0;
        } else if (cc == 4 || cc == 5) {  // compact halves (predicated per-lane)
            #pragma unroll
            for (int jj = 0; jj < 16; ++jj) {
                const int j = (cc - 4) * 16 + jj;
                const bool     p = db[j] <= probeB;
                const uint64_t m = __ballot(p);
                if (p && haveB) {
                    const int slot = (int)baseB + (int)__popcll(m & lmlt);
                    ckey[w][slot] = (((uint64_t)db[j]) << 11) | (uint64_t)(lane + (j << 6));
                }
                baseB += (uint32_t)__builtin_popcountll(m);
            }
            if (cc == 5)
                keyB = (haveB && lane < (int)c1B) ? ckey[w][lane] : ~0ull;
        } else if (cc == 6) {             // bitonic k=2..16 (10 rounds)
            #pragma unroll
            for (int k = 2; k <= 16; k <<= 1) {
                #pragma unroll
                for (int j = k >> 1; j > 0; j >>= 1) {
                    const uint64_t other = __shfl_xor((unsigned long long)keyB, j);
                    const bool takeMin = (((lane & j) == 0) == ((lane & k) == 0));
                    keyB = ((keyB < other) == takeMin) ? keyB : other;
                }
            }
        } else {                          // cc == 7: k=32 (5 rounds) + min-merge
            #pragma unroll
            for (int j = 16; j > 0; j >>= 1) {
                const uint64_t other = __shfl_xor((unsigned long long)keyB, j);
                const bool takeMin = (((lane & j) == 0) == ((lane & 32) == 0));
                keyB = ((keyB < other) == takeMin) ? keyB : other;
            }
            const uint64_t other = __shfl_xor((unsigned long long)keyB, 32);
            const uint64_t mn = keyB < other ? keyB : other;
            const uint64_t mx = keyB < other ? other : keyB;
            keyB = ((lane & 32) == 0) ? mn : mx;
        }

        // --- consume: 4-row max-pool (compiler emits v_max3) ---
        a0.x = fmaxf(fmaxf(fmaxf(fmaxf(a0.x, u00.x), u10.x), u20.x), u30.x);
        a0.y = fmaxf(fmaxf(fmaxf(fmaxf(a0.y, u00.y), u10.y), u20.y), u30.y);
        a0.z = fmaxf(fmaxf(fmaxf(fmaxf(a0.z, u00.z), u10.z), u20.z), u30.z);
        a0.w = fmaxf(fmaxf(fmaxf(fmaxf(a0.w, u00.w), u10.w), u20.w), u30.w);
        a1.x = fmaxf(fmaxf(fmaxf(fmaxf(a1.x, u01.x), u11.x), u21.x), u31.x);
        a1.y = fmaxf(fmaxf(fmaxf(fmaxf(a1.y, u01.y), u11.y), u21.y), u31.y);
        a1.z = fmaxf(fmaxf(fmaxf(fmaxf(a1.z, u01.z), u11.z), u21.z), u31.z);
        a1.w = fmaxf(fmaxf(fmaxf(fmaxf(a1.w, u01.w), u11.w), u21.w), u31.w);
    }
    {
        vfloat4* orow = (vfloat4*)(out + ((size_t)b * NPTS + iA) * NF);
        __builtin_nontemporal_store(vfloat4{a0.x, a0.y, a0.z, a0.w}, &orow[lane]);
        __builtin_nontemporal_store(vfloat4{a1.x, a1.y, a1.z, a1.w}, &orow[lane + 64]);
    }

    // ================= query B: finish select (rare slow path) + gather =================
    int selvB;
    if (haveB) selvB = (int)(keyB & 0x7FFull);
    else       selvB = selectFull();   // db[] still holds B's distances

    a0 = make_float4(-INFINITY, -INFINITY, -INFINITY, -INFINITY);
    a1 = a0;
    #pragma unroll 4
    for (int jj = 0; jj < 32; jj += 2) {
        const int n0 = __builtin_amdgcn_readlane(selvB, jj)     & (NPTS - 1);
        const int n1 = __builtin_amdgcn_readlane(selvB, jj + 1) & (NPTS - 1);
        const float4* r0 = (const float4*)(xb + (size_t)n0 * NF);
        const float4* r1 = (const float4*)(xb + (size_t)n1 * NF);
        const float4 v00 = r0[lane];
        const float4 v01 = r0[lane + 64];
        const float4 v10 = r1[lane];
        const float4 v11 = r1[lane + 64];
        a0.x = fmaxf(fmaxf(a0.x, v00.x), v10.x);
        a0.y = fmaxf(fmaxf(a0.y, v00.y), v10.y);
        a0.z = fmaxf(fmaxf(a0.z, v00.z), v10.z);
        a0.w = fmaxf(fmaxf(a0.w, v00.w), v10.w);
        a1.x = fmaxf(fmaxf(a1.x, v01.x), v11.x);
        a1.y = fmaxf(fmaxf(a1.y, v01.y), v11.y);
        a1.z = fmaxf(fmaxf(a1.z, v01.z), v11.z);
        a1.w = fmaxf(fmaxf(a1.w, v01.w), v11.w);
    }
    {
        vfloat4* orow = (vfloat4*)(out + ((size_t)b * NPTS + iA + 1) * NF);
        __builtin_nontemporal_store(vfloat4{a0.x, a0.y, a0.z, a0.w}, &orow[lane]);
        __builtin_nontemporal_store(vfloat4{a1.x, a1.y, a1.z, a1.w}, &orow[lane + 64]);
    }
}

extern "C" void kernel_launch(void* const* d_in, const int* in_sizes, int n_in,
                              void* d_out, int out_size, void* d_ws, size_t ws_size,
                              hipStream_t stream) {
    const float* x      = (const float*)d_in[0];   // [8, 2048, 512] f32
    const float* points = (const float*)d_in[1];   // [8, 2048, 3]   f32
    float* out          = (float*)d_out;           // [8, 2048, 512] f32

    pointnetpp_knn_maxpool<<<dim3(BATCHES * (NPTS / (BWAVES * QPW))),
                             dim3(256), 0, stream>>>(x, points, out);
}